// Round 4
// baseline (2742.346 us; speedup 1.0000x reference)
//
#include <hip/hip_runtime.h>

// Wavelet_Convolution: out = relu(phi1 @ (kernel * (phi0 @ (x @ W))))
// N=100000, F=128, NNZ=1.6M per sparse matrix (COO, int32 idx, f32 vals).
//
// Pipeline:
//   1) bf16-MFMA GEMM: X' = x@W  (into d_out)
//   2) bucket_scatter: edges of both matrices -> 128-row buckets
//      (LDS-staged counting, coalesced run writes, 8B packed records)
//   3) spmm_bucket: one block per bucket, 64KB LDS f32 accumulator,
//      ds_add_f32 (bank-conflict-free lane->bank mapping), fused scale/relu.

constexpr int kN = 100000;
constexpr int kF = 128;
constexpr int kNNZ = 1600000;

constexpr int kBuckets = (kN + 127) / 128;                  // 782
constexpr int kBucketCap = 3072;                            // Poisson(2046)+22 sigma
constexpr int kChunk = 16384;                               // edges per scatter block
constexpr int kChunkBlocks = (kNNZ + kChunk - 1) / kChunk;  // 98

typedef short bf16x8 __attribute__((ext_vector_type(8)));
typedef float f32x4 __attribute__((ext_vector_type(4)));
typedef unsigned short ushort4v __attribute__((ext_vector_type(4)));
typedef unsigned short ushort8v __attribute__((ext_vector_type(8)));

__device__ __forceinline__ unsigned short f32_to_bf16(float f) {
    unsigned int u = __float_as_uint(f);
    u += 0x7fffu + ((u >> 16) & 1u);   // round-to-nearest-even
    return (unsigned short)(u >> 16);
}

// ---------------------------------------------------------------------------
// Wt[n][k] = bf16(W[k][n])
// ---------------------------------------------------------------------------
__global__ __launch_bounds__(256) void transpose_w(const float* __restrict__ W,
                                                   unsigned short* __restrict__ Wt) {
    const int e = blockIdx.x * 256 + threadIdx.x;   // grid 64
    const int n = e & 127, k = e >> 7;
    Wt[n * 128 + k] = f32_to_bf16(W[e]);
}

// ---------------------------------------------------------------------------
// GEMM: X' = x @ W via mfma_f32_16x16x32_bf16 (same as round 3, verified).
// ---------------------------------------------------------------------------
__global__ __launch_bounds__(256) void gemm_mfma(const float* __restrict__ x,
                                                 const unsigned short* __restrict__ Wt,
                                                 float* __restrict__ Xp) {
    __shared__ __align__(16) unsigned short xs[64 * 128];
    __shared__ __align__(16) unsigned short wt[128 * 128];

    const int t = threadIdx.x;
    const int rowBase = blockIdx.x * 64;

    {
        const int lrow = t >> 2;
        const int q = t & 3;
        int srow = rowBase + lrow;
        if (srow >= kN) srow = kN - 1;
        const float4* xr = (const float4*)(x + (size_t)srow * kF) + q * 8;
        #pragma unroll
        for (int i = 0; i < 8; ++i) {
            const float4 f = xr[i];
            ushort4v h;
            h.x = f32_to_bf16(f.x); h.y = f32_to_bf16(f.y);
            h.z = f32_to_bf16(f.z); h.w = f32_to_bf16(f.w);
            const int kidx = q * 32 + i * 4;
            *(ushort4v*)&xs[lrow * 128 + (kidx ^ ((lrow & 7) << 3))] = h;
        }
    }
    {
        const ushort8v* Wt8 = (const ushort8v*)Wt;
        #pragma unroll
        for (int i = 0; i < 8; ++i) {
            const int c = i * 256 + t;
            const int n = c >> 4;
            const int kb = (c & 15) * 8;
            *(ushort8v*)&wt[n * 128 + (kb ^ ((n & 7) << 3))] = Wt8[c];
        }
    }
    __syncthreads();

    const int w = t >> 6;
    const int l = t & 63;
    const int lr = l & 15;
    const int lq = l >> 4;

    f32x4 acc[8];
    #pragma unroll
    for (int n = 0; n < 8; ++n) acc[n] = (f32x4){0.f, 0.f, 0.f, 0.f};

    const int arow = w * 16 + lr;
    #pragma unroll
    for (int ks = 0; ks < 4; ++ks) {
        const int akidx = ks * 32 + lq * 8;
        const bf16x8 a = *(const bf16x8*)&xs[arow * 128 + (akidx ^ ((arow & 7) << 3))];
        #pragma unroll
        for (int n = 0; n < 8; ++n) {
            const int bn = n * 16 + lr;
            const bf16x8 b = *(const bf16x8*)&wt[bn * 128 + (akidx ^ ((bn & 7) << 3))];
            acc[n] = __builtin_amdgcn_mfma_f32_16x16x32_bf16(a, b, acc[n], 0, 0, 0);
        }
    }

    #pragma unroll
    for (int j = 0; j < 4; ++j) {
        const int row = rowBase + w * 16 + lq * 4 + j;
        if (row < kN) {
            float* orow = Xp + (size_t)row * kF + lr;
            #pragma unroll
            for (int n = 0; n < 8; ++n) orow[n * 16] = acc[n][j];
        }
    }
}

// ---------------------------------------------------------------------------
// Cursor init: gcur[b] = b * kBucketCap for both matrices.
// ---------------------------------------------------------------------------
__global__ __launch_bounds__(256) void init_cursors(int* __restrict__ g0,
                                                    int* __restrict__ g1) {
    const int i = blockIdx.x * 256 + threadIdx.x;
    if (i < kBuckets) {
        g0[i] = i * kBucketCap;
        g1[i] = i * kBucketCap;
    }
}

// ---------------------------------------------------------------------------
// Bucket scatter: edges -> per-bucket regions (contiguous runs per block).
// Record: hi32 = f32 val, lo32 = (localrow&127)<<17 | col (col < 2^17).
// ---------------------------------------------------------------------------
__global__ __launch_bounds__(256) void bucket_scatter(
    const int* __restrict__ r0, const int* __restrict__ c0, const float* __restrict__ v0,
    const int* __restrict__ r1, const int* __restrict__ c1, const float* __restrict__ v1,
    int* __restrict__ gc0, int* __restrict__ gc1,
    unsigned long long* __restrict__ s0, unsigned long long* __restrict__ s1) {
    const int b = blockIdx.x;
    const bool m1 = b >= kChunkBlocks;
    const int cb = m1 ? b - kChunkBlocks : b;
    const int* rows = m1 ? r1 : r0;
    const int* cols = m1 ? c1 : c0;
    const float* vals = m1 ? v1 : v0;
    int* gcur = m1 ? gc1 : gc0;
    unsigned long long* stg = m1 ? s1 : s0;

    __shared__ int hist[kBuckets];
    __shared__ int hbase[kBuckets];
    const int t = threadIdx.x;

    for (int i = t; i < kBuckets; i += 256) hist[i] = 0;
    __syncthreads();

    const int base0 = cb * kChunk;
    for (int j = 0; j < kChunk; j += 256) {
        const int idx = base0 + j + t;
        if (idx < kNNZ) atomicAdd(&hist[rows[idx] >> 7], 1);
    }
    __syncthreads();

    for (int i = t; i < kBuckets; i += 256) {
        const int c = hist[i];
        hbase[i] = c ? atomicAdd(&gcur[i], c) : 0;
        hist[i] = 0;
    }
    __syncthreads();

    for (int j = 0; j < kChunk; j += 256) {
        const int idx = base0 + j + t;
        if (idx < kNNZ) {
            const int r = rows[idx];
            const int bk = r >> 7;
            const int pos = hbase[bk] + atomicAdd(&hist[bk], 1);
            const unsigned int key = ((unsigned int)(r & 127) << 17) | (unsigned int)cols[idx];
            stg[pos] = ((unsigned long long)__float_as_uint(vals[idx]) << 32) | key;
        }
    }
}

// ---------------------------------------------------------------------------
// SpMM over buckets: block b accumulates rows [128b,128b+128) in 64KB LDS.
// 8 workers of 32 lanes; 2 edges per worker per iter (16 consecutive recs).
// Lane handles features lane, lane+32, lane+64, lane+96 -> ds_add_f32 hits
// bank (lane&31): 2 lanes/bank across the wave = conflict-free.
// ---------------------------------------------------------------------------
template <bool ROW_SCALE, bool RELU>
__global__ __launch_bounds__(256) void spmm_bucket(const int* __restrict__ gcur,
                                                   const unsigned long long* __restrict__ stg,
                                                   const float* __restrict__ scale,
                                                   const float* __restrict__ Xin,
                                                   float* __restrict__ Xout) {
    __shared__ float acc[128 * kF];   // 64 KB
    const int t = threadIdx.x;
    const int b = blockIdx.x;

    float4* acc4 = (float4*)acc;
    for (int i = t; i < 128 * kF / 4; i += 256)
        acc4[i] = make_float4(0.f, 0.f, 0.f, 0.f);
    __syncthreads();

    const int start = b * kBucketCap;
    const int end = gcur[b];                 // start + bucket count
    const int worker = t >> 5;
    const int lane = t & 31;

    for (int i = start + worker * 2; i < end; i += 16) {
        const unsigned long long p0 = stg[i];
        const unsigned long long p1 = (i + 1 < end) ? stg[i + 1] : 0ULL;  // val=0 -> no-op

        const unsigned int k0 = (unsigned int)p0;
        const float va = __uint_as_float((unsigned int)(p0 >> 32));
        const int ca = k0 & 0x1FFFF;
        const int ra = (int)(k0 >> 17);

        const unsigned int k1 = (unsigned int)p1;
        const float vb = __uint_as_float((unsigned int)(p1 >> 32));
        const int cb = k1 & 0x1FFFF;
        const int rb = (int)(k1 >> 17);

        const float* xa = Xin + (size_t)ca * kF + lane;
        const float* xb = Xin + (size_t)cb * kF + lane;
        const float a0 = xa[0], a1 = xa[32], a2 = xa[64], a3 = xa[96];
        const float b0 = xb[0], b1 = xb[32], b2 = xb[64], b3 = xb[96];

        float* apa = acc + ra * kF + lane;
        float* apb = acc + rb * kF + lane;
        atomicAdd(apa +  0, va * a0);
        atomicAdd(apa + 32, va * a1);
        atomicAdd(apa + 64, va * a2);
        atomicAdd(apa + 96, va * a3);
        atomicAdd(apb +  0, vb * b0);
        atomicAdd(apb + 32, vb * b1);
        atomicAdd(apb + 64, vb * b2);
        atomicAdd(apb + 96, vb * b3);
    }
    __syncthreads();

    // writeout: 128 rows x 32 float4, fused scale/relu
    const int rowBase = b * 128;
    for (int i = t; i < 128 * 32; i += 256) {
        const int lr = i >> 5;
        const int row = rowBase + lr;
        if (row < kN) {
            float4 vv = acc4[i];
            if (ROW_SCALE) {
                const float k = scale[row];
                vv.x *= k; vv.y *= k; vv.z *= k; vv.w *= k;
            }
            if (RELU) {
                vv.x = fmaxf(vv.x, 0.f); vv.y = fmaxf(vv.y, 0.f);
                vv.z = fmaxf(vv.z, 0.f); vv.w = fmaxf(vv.w, 0.f);
            }
            ((float4*)Xout)[(size_t)row * 32 + (i & 31)] = vv;
        }
    }
}

extern "C" void kernel_launch(void* const* d_in, const int* in_sizes, int n_in,
                              void* d_out, int out_size, void* d_ws, size_t ws_size,
                              hipStream_t stream) {
    const float* x    = (const float*)d_in[0];
    const float* W    = (const float*)d_in[1];
    const float* kern = (const float*)d_in[2];
    const int*   p0r  = (const int*)d_in[3];
    const int*   p0c  = (const int*)d_in[4];
    const float* p0v  = (const float*)d_in[5];
    const int*   p1r  = (const int*)d_in[6];
    const int*   p1c  = (const int*)d_in[7];
    const float* p1v  = (const float*)d_in[8];
    float* out = (float*)d_out;                // doubles as X' before final write

    // ws layout (16B-aligned slabs)
    char* w = (char*)d_ws;
    size_t off = 0;
    float* Xt = (float*)(w + off);                    off += (size_t)kN * kF * 4;  // 51.2 MB
    unsigned short* Wt = (unsigned short*)(w + off);  off += 128 * 128 * 2;        // 32 KB
    int* gcur0 = (int*)(w + off);                     off += 4096;
    int* gcur1 = (int*)(w + off);                     off += 4096;
    unsigned long long* stg0 = (unsigned long long*)(w + off);
    off += (size_t)kBuckets * kBucketCap * 8;                                      // 19.2 MB
    unsigned long long* stg1 = (unsigned long long*)(w + off);
    off += (size_t)kBuckets * kBucketCap * 8;                                      // 19.2 MB

    // 1) X' = x @ W -> d_out
    transpose_w<<<64, 256, 0, stream>>>(W, Wt);
    gemm_mfma<<<(kN + 63) / 64, 256, 0, stream>>>(x, Wt, out);

    // 2) bucket both edge lists
    init_cursors<<<(kBuckets + 255) / 256, 256, 0, stream>>>(gcur0, gcur1);
    bucket_scatter<<<2 * kChunkBlocks, 256, 0, stream>>>(p0r, p0c, p0v, p1r, p1c, p1v,
                                                         gcur0, gcur1, stg0, stg1);

    // 3) Xt = kernel * (phi0 @ X')
    spmm_bucket<true, false><<<kBuckets, 256, 0, stream>>>(gcur0, stg0, kern, out, Xt);

    // 4) out = relu(phi1 @ Xt)
    spmm_bucket<false, true><<<kBuckets, 256, 0, stream>>>(gcur1, stg1, nullptr, Xt, out);
}

// Round 5
// 348.554 us; speedup vs baseline: 7.8678x; 7.8678x over previous
//
#include <hip/hip_runtime.h>

// Wavelet_Convolution: out = relu(phi1 @ (kernel * (phi0 @ (x @ W))))
// N=100000, F=128, NNZ=1.6M per sparse matrix (COO, int32 idx, f32 vals).
//
// Pipeline:
//   1) bf16-MFMA GEMM: X' = x@W (into d_out)
//   2) bucket_scatter: edges -> 128-row buckets (contiguous run writes, low
//      write amplification; 8B packed records (localrow|col, val))
//   3) bucket_sort: per-bucket LDS counting sort -> exact row order in place,
//      emits per-row [rs, re) bounds. (bucket-major + sorted = global CSR)
//   4) spmm_csr: 32 lanes/row gather SpMM (coalesced rec load + shuffle
//      broadcast + 4-wide float4 gathers), fused kernel-scale / relu.

constexpr int kN = 100000;
constexpr int kF = 128;
constexpr int kNNZ = 1600000;

constexpr int kBuckets = (kN + 127) / 128;                  // 782
constexpr int kBucketCap = 3072;                            // Poisson(2046)+22 sigma
constexpr int kChunk = 16384;                               // edges per scatter block
constexpr int kChunkBlocks = (kNNZ + kChunk - 1) / kChunk;  // 98

typedef short bf16x8 __attribute__((ext_vector_type(8)));
typedef float f32x4 __attribute__((ext_vector_type(4)));
typedef unsigned short ushort4v __attribute__((ext_vector_type(4)));
typedef unsigned short ushort8v __attribute__((ext_vector_type(8)));

__device__ __forceinline__ unsigned short f32_to_bf16(float f) {
    unsigned int u = __float_as_uint(f);
    u += 0x7fffu + ((u >> 16) & 1u);   // round-to-nearest-even
    return (unsigned short)(u >> 16);
}

// ---------------------------------------------------------------------------
// Wt[n][k] = bf16(W[k][n])
// ---------------------------------------------------------------------------
__global__ __launch_bounds__(256) void transpose_w(const float* __restrict__ W,
                                                   unsigned short* __restrict__ Wt) {
    const int e = blockIdx.x * 256 + threadIdx.x;   // grid 64
    const int n = e & 127, k = e >> 7;
    Wt[n * 128 + k] = f32_to_bf16(W[e]);
}

// ---------------------------------------------------------------------------
// GEMM: X' = x @ W via mfma_f32_16x16x32_bf16 (verified in rounds 2-4).
// ---------------------------------------------------------------------------
__global__ __launch_bounds__(256) void gemm_mfma(const float* __restrict__ x,
                                                 const unsigned short* __restrict__ Wt,
                                                 float* __restrict__ Xp) {
    __shared__ __align__(16) unsigned short xs[64 * 128];
    __shared__ __align__(16) unsigned short wt[128 * 128];

    const int t = threadIdx.x;
    const int rowBase = blockIdx.x * 64;

    {
        const int lrow = t >> 2;
        const int q = t & 3;
        int srow = rowBase + lrow;
        if (srow >= kN) srow = kN - 1;
        const float4* xr = (const float4*)(x + (size_t)srow * kF) + q * 8;
        #pragma unroll
        for (int i = 0; i < 8; ++i) {
            const float4 f = xr[i];
            ushort4v h;
            h.x = f32_to_bf16(f.x); h.y = f32_to_bf16(f.y);
            h.z = f32_to_bf16(f.z); h.w = f32_to_bf16(f.w);
            const int kidx = q * 32 + i * 4;
            *(ushort4v*)&xs[lrow * 128 + (kidx ^ ((lrow & 7) << 3))] = h;
        }
    }
    {
        const ushort8v* Wt8 = (const ushort8v*)Wt;
        #pragma unroll
        for (int i = 0; i < 8; ++i) {
            const int c = i * 256 + t;
            const int n = c >> 4;
            const int kb = (c & 15) * 8;
            *(ushort8v*)&wt[n * 128 + (kb ^ ((n & 7) << 3))] = Wt8[c];
        }
    }
    __syncthreads();

    const int w = t >> 6;
    const int l = t & 63;
    const int lr = l & 15;
    const int lq = l >> 4;

    f32x4 acc[8];
    #pragma unroll
    for (int n = 0; n < 8; ++n) acc[n] = (f32x4){0.f, 0.f, 0.f, 0.f};

    const int arow = w * 16 + lr;
    #pragma unroll
    for (int ks = 0; ks < 4; ++ks) {
        const int akidx = ks * 32 + lq * 8;
        const bf16x8 a = *(const bf16x8*)&xs[arow * 128 + (akidx ^ ((arow & 7) << 3))];
        #pragma unroll
        for (int n = 0; n < 8; ++n) {
            const int bn = n * 16 + lr;
            const bf16x8 b = *(const bf16x8*)&wt[bn * 128 + (akidx ^ ((bn & 7) << 3))];
            acc[n] = __builtin_amdgcn_mfma_f32_16x16x32_bf16(a, b, acc[n], 0, 0, 0);
        }
    }

    #pragma unroll
    for (int j = 0; j < 4; ++j) {
        const int row = rowBase + w * 16 + lq * 4 + j;
        if (row < kN) {
            float* orow = Xp + (size_t)row * kF + lr;
            #pragma unroll
            for (int n = 0; n < 8; ++n) orow[n * 16] = acc[n][j];
        }
    }
}

// ---------------------------------------------------------------------------
// Cursor init: gcur[b] = b * kBucketCap for both matrices.
// ---------------------------------------------------------------------------
__global__ __launch_bounds__(256) void init_cursors(int* __restrict__ g0,
                                                    int* __restrict__ g1) {
    const int i = blockIdx.x * 256 + threadIdx.x;
    if (i < kBuckets) {
        g0[i] = i * kBucketCap;
        g1[i] = i * kBucketCap;
    }
}

// ---------------------------------------------------------------------------
// Bucket scatter: edges -> per-bucket regions (contiguous runs per block).
// Record: hi32 = f32 val, lo32 = (localrow&127)<<17 | col (col < 2^17).
// ---------------------------------------------------------------------------
__global__ __launch_bounds__(256) void bucket_scatter(
    const int* __restrict__ r0, const int* __restrict__ c0, const float* __restrict__ v0,
    const int* __restrict__ r1, const int* __restrict__ c1, const float* __restrict__ v1,
    int* __restrict__ gc0, int* __restrict__ gc1,
    unsigned long long* __restrict__ s0, unsigned long long* __restrict__ s1) {
    const int b = blockIdx.x;
    const bool m1 = b >= kChunkBlocks;
    const int cb = m1 ? b - kChunkBlocks : b;
    const int* rows = m1 ? r1 : r0;
    const int* cols = m1 ? c1 : c0;
    const float* vals = m1 ? v1 : v0;
    int* gcur = m1 ? gc1 : gc0;
    unsigned long long* stg = m1 ? s1 : s0;

    __shared__ int hist[kBuckets];
    __shared__ int hbase[kBuckets];
    const int t = threadIdx.x;

    for (int i = t; i < kBuckets; i += 256) hist[i] = 0;
    __syncthreads();

    const int base0 = cb * kChunk;
    for (int j = 0; j < kChunk; j += 256) {
        const int idx = base0 + j + t;
        if (idx < kNNZ) atomicAdd(&hist[rows[idx] >> 7], 1);
    }
    __syncthreads();

    for (int i = t; i < kBuckets; i += 256) {
        const int c = hist[i];
        hbase[i] = c ? atomicAdd(&gcur[i], c) : 0;
        hist[i] = 0;
    }
    __syncthreads();

    for (int j = 0; j < kChunk; j += 256) {
        const int idx = base0 + j + t;
        if (idx < kNNZ) {
            const int r = rows[idx];
            const int bk = r >> 7;
            const int pos = hbase[bk] + atomicAdd(&hist[bk], 1);
            const unsigned int key = ((unsigned int)(r & 127) << 17) | (unsigned int)cols[idx];
            stg[pos] = ((unsigned long long)__float_as_uint(vals[idx]) << 32) | key;
        }
    }
}

// ---------------------------------------------------------------------------
// Per-bucket LDS counting sort (in place) + emit per-row [rs, re).
// Grid: 2*kBuckets blocks (both matrices). LDS: 24KB recs + small tables.
// ---------------------------------------------------------------------------
__global__ __launch_bounds__(256) void bucket_sort(
    const int* __restrict__ gc0, const int* __restrict__ gc1,
    unsigned long long* __restrict__ s0, unsigned long long* __restrict__ s1,
    int* __restrict__ rs0, int* __restrict__ re0,
    int* __restrict__ rs1, int* __restrict__ re1) {
    __shared__ unsigned long long recs[kBucketCap];  // 24 KB
    __shared__ int hist[128];
    __shared__ int sc[128];
    __shared__ int cur[128];

    const int b = blockIdx.x;
    const bool m1 = b >= kBuckets;
    const int bk = m1 ? b - kBuckets : b;
    const int* gcur = m1 ? gc1 : gc0;
    unsigned long long* stg = m1 ? s1 : s0;
    int* rs = m1 ? rs1 : rs0;
    int* re = m1 ? re1 : re0;

    const int t = threadIdx.x;
    const int start = bk * kBucketCap;
    const int nrec = gcur[bk] - start;

    if (t < 128) hist[t] = 0;
    __syncthreads();

    // load records to LDS + local-row histogram
    for (int i = t; i < nrec; i += 256) {
        const unsigned long long p = stg[start + i];
        recs[i] = p;
        atomicAdd(&hist[((unsigned int)p >> 17) & 127], 1);
    }
    __syncthreads();

    // inclusive scan of 128 bins (Hillis-Steele, whole block in barriers)
    const int v = (t < 128) ? hist[t] : 0;
    if (t < 128) sc[t] = v;
    __syncthreads();
    #pragma unroll
    for (int off = 1; off < 128; off <<= 1) {
        const int add = (t < 128 && t >= off) ? sc[t - off] : 0;
        __syncthreads();
        if (t < 128) sc[t] += add;
        __syncthreads();
    }
    if (t < 128) {
        const int ex = sc[t] - v;      // exclusive
        cur[t] = ex;
        const int row = bk * 128 + t;
        if (row < kN) {
            rs[row] = start + ex;
            re[row] = start + sc[t];
        }
    }
    __syncthreads();

    // scatter back in row-sorted order (same region; all reads already in LDS)
    for (int i = t; i < nrec; i += 256) {
        const unsigned long long p = recs[i];
        const int lr = (int)(((unsigned int)p >> 17) & 127);
        const int pos = atomicAdd(&cur[lr], 1);
        stg[start + pos] = p;
    }
}

// ---------------------------------------------------------------------------
// Gather SpMM: 32 lanes per row. Coalesced rec load per 32-edge chunk,
// shuffle-broadcast, 4-wide unrolled float4 gathers.
// Record cols are in the low 17 bits.
// ---------------------------------------------------------------------------
template <bool ROW_SCALE, bool RELU>
__global__ __launch_bounds__(256) void spmm_csr(const int* __restrict__ rs,
                                                const int* __restrict__ re,
                                                const unsigned long long* __restrict__ rec,
                                                const float* __restrict__ scale,
                                                const float* __restrict__ Xin,
                                                float* __restrict__ Xout) {
    const int tid = blockIdx.x * 256 + threadIdx.x;
    const int r = tid >> 5;          // grid = kN*32/256 exactly
    const int lane = tid & 31;

    const int s = rs[r];
    const int e = re[r];

    const float4* Xin4 = (const float4*)Xin;
    float4 acc = make_float4(0.f, 0.f, 0.f, 0.f);

    for (int base = s; base < e; base += 32) {
        int cl = 0;
        float vl = 0.f;
        if (base + lane < e) {
            const unsigned long long p = rec[base + lane];
            cl = (int)((unsigned int)p & 0x1FFFF);
            vl = __uint_as_float((unsigned int)(p >> 32));
        }
        const int m4 = (min(32, e - base) + 3) & ~3;
        for (int j = 0; j < m4; j += 4) {
            const int c0 = __shfl(cl, j, 32);
            const int c1 = __shfl(cl, j + 1, 32);
            const int c2 = __shfl(cl, j + 2, 32);
            const int c3 = __shfl(cl, j + 3, 32);
            const float w0 = __shfl(vl, j, 32);
            const float w1 = __shfl(vl, j + 1, 32);
            const float w2 = __shfl(vl, j + 2, 32);
            const float w3 = __shfl(vl, j + 3, 32);
            const float4 x0 = Xin4[(size_t)c0 * 32 + lane];
            const float4 x1 = Xin4[(size_t)c1 * 32 + lane];
            const float4 x2 = Xin4[(size_t)c2 * 32 + lane];
            const float4 x3 = Xin4[(size_t)c3 * 32 + lane];
            acc.x = fmaf(w0, x0.x, acc.x); acc.y = fmaf(w0, x0.y, acc.y);
            acc.z = fmaf(w0, x0.z, acc.z); acc.w = fmaf(w0, x0.w, acc.w);
            acc.x = fmaf(w1, x1.x, acc.x); acc.y = fmaf(w1, x1.y, acc.y);
            acc.z = fmaf(w1, x1.z, acc.z); acc.w = fmaf(w1, x1.w, acc.w);
            acc.x = fmaf(w2, x2.x, acc.x); acc.y = fmaf(w2, x2.y, acc.y);
            acc.z = fmaf(w2, x2.z, acc.z); acc.w = fmaf(w2, x2.w, acc.w);
            acc.x = fmaf(w3, x3.x, acc.x); acc.y = fmaf(w3, x3.y, acc.y);
            acc.z = fmaf(w3, x3.z, acc.z); acc.w = fmaf(w3, x3.w, acc.w);
        }
    }
    if (ROW_SCALE) {
        const float k = scale[r];
        acc.x *= k; acc.y *= k; acc.z *= k; acc.w *= k;
    }
    if (RELU) {
        acc.x = fmaxf(acc.x, 0.f); acc.y = fmaxf(acc.y, 0.f);
        acc.z = fmaxf(acc.z, 0.f); acc.w = fmaxf(acc.w, 0.f);
    }
    ((float4*)Xout)[(size_t)r * 32 + lane] = acc;
}

extern "C" void kernel_launch(void* const* d_in, const int* in_sizes, int n_in,
                              void* d_out, int out_size, void* d_ws, size_t ws_size,
                              hipStream_t stream) {
    const float* x    = (const float*)d_in[0];
    const float* W    = (const float*)d_in[1];
    const float* kern = (const float*)d_in[2];
    const int*   p0r  = (const int*)d_in[3];
    const int*   p0c  = (const int*)d_in[4];
    const float* p0v  = (const float*)d_in[5];
    const int*   p1r  = (const int*)d_in[6];
    const int*   p1c  = (const int*)d_in[7];
    const float* p1v  = (const float*)d_in[8];
    float* out = (float*)d_out;                // doubles as X' before final write

    // ws layout (16B-aligned slabs), total ~92 MB
    char* w = (char*)d_ws;
    size_t off = 0;
    float* Xt = (float*)(w + off);                    off += (size_t)kN * kF * 4;  // 51.2 MB
    unsigned short* Wt = (unsigned short*)(w + off);  off += 128 * 128 * 2;        // 32 KB
    int* gcur0 = (int*)(w + off);                     off += 4096;
    int* gcur1 = (int*)(w + off);                     off += 4096;
    int* rs0 = (int*)(w + off);                       off += (size_t)kN * 4;
    int* re0 = (int*)(w + off);                       off += (size_t)kN * 4;
    int* rs1 = (int*)(w + off);                       off += (size_t)kN * 4;
    int* re1 = (int*)(w + off);                       off += (size_t)kN * 4;      // 1.6 MB
    unsigned long long* stg0 = (unsigned long long*)(w + off);
    off += (size_t)kBuckets * kBucketCap * 8;                                      // 19.2 MB
    unsigned long long* stg1 = (unsigned long long*)(w + off);
    off += (size_t)kBuckets * kBucketCap * 8;                                      // 19.2 MB

    const int rowBlocks = kN * 32 / 256;       // 12500

    // 1) X' = x @ W -> d_out
    transpose_w<<<64, 256, 0, stream>>>(W, Wt);
    gemm_mfma<<<(kN + 63) / 64, 256, 0, stream>>>(x, Wt, out);

    // 2) bucket both edge lists, then sort each bucket to exact row order
    init_cursors<<<(kBuckets + 255) / 256, 256, 0, stream>>>(gcur0, gcur1);
    bucket_scatter<<<2 * kChunkBlocks, 256, 0, stream>>>(p0r, p0c, p0v, p1r, p1c, p1v,
                                                         gcur0, gcur1, stg0, stg1);
    bucket_sort<<<2 * kBuckets, 256, 0, stream>>>(gcur0, gcur1, stg0, stg1,
                                                  rs0, re0, rs1, re1);

    // 3) Xt = kernel * (phi0 @ X')
    spmm_csr<true, false><<<rowBlocks, 256, 0, stream>>>(rs0, re0, stg0, kern, out, Xt);

    // 4) out = relu(phi1 @ Xt)
    spmm_csr<false, true><<<rowBlocks, 256, 0, stream>>>(rs1, re1, stg1, nullptr, Xt, out);
}

// Round 6
// 325.756 us; speedup vs baseline: 8.4184x; 1.0700x over previous
//
#include <hip/hip_runtime.h>

// Wavelet_Convolution: out = relu(phi1 @ (kernel * (phi0 @ (x @ W))))
// N=100000, F=128, NNZ=1.6M per sparse matrix (COO, int32 idx, f32 vals).
//
// Pipeline (5 dispatches):
//   1) transpose_w (+cursor init): Wt = bf16(W^T)
//   2) fused_gemm_scatter: [blocks 0..1562] X' = x@W (bf16 MFMA)
//                          [blocks 1563..1954] edges -> 256-row buckets
//      (independent work fused so the latency-bound scatter hides under MFMA)
//   3) bucket_sort: per-bucket LDS counting sort -> exact row order in place,
//      emits per-row [rs, re) bounds (bucket-major + sorted = global CSR)
//   4) spmm_csr: Xt = kernel * (phi0 @ X')   (gather, fused row-scale)
//   5) spmm_csr: out = relu(phi1 @ Xt)       (gather, fused relu)

constexpr int kN = 100000;
constexpr int kF = 128;
constexpr int kNNZ = 1600000;

constexpr int kBuckets = (kN + 255) / 256;                  // 391 (256-row buckets)
constexpr int kBucketCap = 4608;                            // mean 4096, sigma 64: +8 sigma
constexpr int kChunk = 8192;                                // edges per scatter block
constexpr int kChunkBlocks = (kNNZ + kChunk - 1) / kChunk;  // 196
constexpr int kGemmBlocks = (kN + 63) / 64;                 // 1563

typedef short bf16x8 __attribute__((ext_vector_type(8)));
typedef float f32x4 __attribute__((ext_vector_type(4)));
typedef unsigned short ushort4v __attribute__((ext_vector_type(4)));
typedef unsigned short ushort8v __attribute__((ext_vector_type(8)));

__device__ __forceinline__ unsigned short f32_to_bf16(float f) {
    unsigned int u = __float_as_uint(f);
    u += 0x7fffu + ((u >> 16) & 1u);   // round-to-nearest-even
    return (unsigned short)(u >> 16);
}

// ---------------------------------------------------------------------------
// Wt[n][k] = bf16(W[k][n]); block 0 also inits bucket cursors.
// ---------------------------------------------------------------------------
__global__ __launch_bounds__(256) void transpose_w(const float* __restrict__ W,
                                                   unsigned short* __restrict__ Wt,
                                                   int* __restrict__ g0,
                                                   int* __restrict__ g1) {
    const int t = threadIdx.x;
    const int e = blockIdx.x * 256 + t;   // grid 64
    const int n = e & 127, k = e >> 7;
    Wt[n * 128 + k] = f32_to_bf16(W[e]);
    if (blockIdx.x == 0) {
        for (int i = t; i < kBuckets; i += 256) {
            g0[i] = i * kBucketCap;
            g1[i] = i * kBucketCap;
        }
    }
}

// ---------------------------------------------------------------------------
// Fused: GEMM (blocks 0..kGemmBlocks-1) + bucket scatter (rest).
// GEMM: X' = x @ W via mfma_f32_16x16x32_bf16 (verified rounds 2-5).
// Scatter record: hi32 = f32 val, lo32 = (localrow&255)<<17 | col (col<2^17).
// ---------------------------------------------------------------------------
__global__ __launch_bounds__(256) void fused_gemm_scatter(
    const float* __restrict__ x, const unsigned short* __restrict__ Wt,
    float* __restrict__ Xp,
    const int* __restrict__ r0, const int* __restrict__ c0, const float* __restrict__ v0,
    const int* __restrict__ r1, const int* __restrict__ c1, const float* __restrict__ v1,
    int* __restrict__ gc0, int* __restrict__ gc1,
    unsigned long long* __restrict__ s0, unsigned long long* __restrict__ s1) {
    __shared__ __align__(16) char smem[64 * 128 * 2 + 128 * 128 * 2];  // 48 KB
    const int t = threadIdx.x;

    if (blockIdx.x < kGemmBlocks) {
        // ================= GEMM branch =================
        unsigned short* xs = (unsigned short*)smem;            // 64x128
        unsigned short* wt = xs + 64 * 128;                    // 128x128
        const int rowBase = blockIdx.x * 64;

        {
            const int lrow = t >> 2;
            const int q = t & 3;
            int srow = rowBase + lrow;
            if (srow >= kN) srow = kN - 1;
            const float4* xr = (const float4*)(x + (size_t)srow * kF) + q * 8;
            #pragma unroll
            for (int i = 0; i < 8; ++i) {
                const float4 f = xr[i];
                ushort4v h;
                h.x = f32_to_bf16(f.x); h.y = f32_to_bf16(f.y);
                h.z = f32_to_bf16(f.z); h.w = f32_to_bf16(f.w);
                const int kidx = q * 32 + i * 4;
                *(ushort4v*)&xs[lrow * 128 + (kidx ^ ((lrow & 7) << 3))] = h;
            }
        }
        {
            const ushort8v* Wt8 = (const ushort8v*)Wt;
            #pragma unroll
            for (int i = 0; i < 8; ++i) {
                const int c = i * 256 + t;
                const int n = c >> 4;
                const int kb = (c & 15) * 8;
                *(ushort8v*)&wt[n * 128 + (kb ^ ((n & 7) << 3))] = Wt8[c];
            }
        }
        __syncthreads();

        const int w = t >> 6;
        const int l = t & 63;
        const int lr = l & 15;
        const int lq = l >> 4;

        f32x4 acc[8];
        #pragma unroll
        for (int n = 0; n < 8; ++n) acc[n] = (f32x4){0.f, 0.f, 0.f, 0.f};

        const int arow = w * 16 + lr;
        #pragma unroll
        for (int ks = 0; ks < 4; ++ks) {
            const int akidx = ks * 32 + lq * 8;
            const bf16x8 a = *(const bf16x8*)&xs[arow * 128 + (akidx ^ ((arow & 7) << 3))];
            #pragma unroll
            for (int n = 0; n < 8; ++n) {
                const int bn = n * 16 + lr;
                const bf16x8 b = *(const bf16x8*)&wt[bn * 128 + (akidx ^ ((bn & 7) << 3))];
                acc[n] = __builtin_amdgcn_mfma_f32_16x16x32_bf16(a, b, acc[n], 0, 0, 0);
            }
        }

        #pragma unroll
        for (int j = 0; j < 4; ++j) {
            const int row = rowBase + w * 16 + lq * 4 + j;
            if (row < kN) {
                float* orow = Xp + (size_t)row * kF + lr;
                #pragma unroll
                for (int n = 0; n < 8; ++n) orow[n * 16] = acc[n][j];
            }
        }
    } else {
        // ================= scatter branch =================
        int* hist = (int*)smem;                 // kBuckets
        int* hbase = hist + kBuckets;           // kBuckets
        const int b = blockIdx.x - kGemmBlocks;
        const bool m1 = b >= kChunkBlocks;
        const int cb = m1 ? b - kChunkBlocks : b;
        const int* rows = m1 ? r1 : r0;
        const int* cols = m1 ? c1 : c0;
        const float* vals = m1 ? v1 : v0;
        int* gcur = m1 ? gc1 : gc0;
        unsigned long long* stg = m1 ? s1 : s0;

        for (int i = t; i < kBuckets; i += 256) hist[i] = 0;
        __syncthreads();

        const int base0 = cb * kChunk;
        for (int j = 0; j < kChunk; j += 256) {
            const int idx = base0 + j + t;
            if (idx < kNNZ) atomicAdd(&hist[rows[idx] >> 8], 1);
        }
        __syncthreads();

        for (int i = t; i < kBuckets; i += 256) {
            const int c = hist[i];
            hbase[i] = c ? atomicAdd(&gcur[i], c) : 0;
            hist[i] = 0;
        }
        __syncthreads();

        for (int j = 0; j < kChunk; j += 256) {
            const int idx = base0 + j + t;
            if (idx < kNNZ) {
                const int r = rows[idx];
                const int bk = r >> 8;
                const int pos = hbase[bk] + atomicAdd(&hist[bk], 1);
                const unsigned int key =
                    ((unsigned int)(r & 255) << 17) | (unsigned int)cols[idx];
                stg[pos] = ((unsigned long long)__float_as_uint(vals[idx]) << 32) | key;
            }
        }
    }
}

// ---------------------------------------------------------------------------
// Per-bucket LDS counting sort (in place) + emit per-row [rs, re).
// Grid: 2*kBuckets blocks (both matrices). LDS: 36.9KB recs + 3KB tables.
// ---------------------------------------------------------------------------
__global__ __launch_bounds__(256) void bucket_sort(
    const int* __restrict__ gc0, const int* __restrict__ gc1,
    unsigned long long* __restrict__ s0, unsigned long long* __restrict__ s1,
    int* __restrict__ rs0, int* __restrict__ re0,
    int* __restrict__ rs1, int* __restrict__ re1) {
    __shared__ unsigned long long recs[kBucketCap];  // 36.9 KB
    __shared__ int hist[256];
    __shared__ int sc[256];
    __shared__ int cur[256];

    const int b = blockIdx.x;
    const bool m1 = b >= kBuckets;
    const int bk = m1 ? b - kBuckets : b;
    const int* gcur = m1 ? gc1 : gc0;
    unsigned long long* stg = m1 ? s1 : s0;
    int* rs = m1 ? rs1 : rs0;
    int* re = m1 ? re1 : re0;

    const int t = threadIdx.x;
    const int start = bk * kBucketCap;
    const int nrec = gcur[bk] - start;

    hist[t] = 0;
    __syncthreads();

    // load records to LDS + local-row histogram
    for (int i = t; i < nrec; i += 256) {
        const unsigned long long p = stg[start + i];
        recs[i] = p;
        atomicAdd(&hist[((unsigned int)p >> 17) & 255], 1);
    }
    __syncthreads();

    // inclusive scan of 256 bins (Hillis-Steele over the whole block)
    const int v = hist[t];
    sc[t] = v;
    __syncthreads();
    #pragma unroll
    for (int off = 1; off < 256; off <<= 1) {
        const int add = (t >= off) ? sc[t - off] : 0;
        __syncthreads();
        sc[t] += add;
        __syncthreads();
    }
    {
        const int ex = sc[t] - v;      // exclusive
        cur[t] = ex;
        const int row = bk * 256 + t;
        if (row < kN) {
            rs[row] = start + ex;
            re[row] = start + sc[t];
        }
    }
    __syncthreads();

    // scatter back in row-sorted order (all reads already in LDS)
    for (int i = t; i < nrec; i += 256) {
        const unsigned long long p = recs[i];
        const int lr = (int)(((unsigned int)p >> 17) & 255);
        const int pos = atomicAdd(&cur[lr], 1);
        stg[start + pos] = p;
    }
}

// ---------------------------------------------------------------------------
// Gather SpMM: 32 lanes per row. Coalesced rec load per 32-edge chunk,
// shuffle-broadcast, 4-wide unrolled float4 gathers.
// ---------------------------------------------------------------------------
template <bool ROW_SCALE, bool RELU>
__global__ __launch_bounds__(256) void spmm_csr(const int* __restrict__ rs,
                                                const int* __restrict__ re,
                                                const unsigned long long* __restrict__ rec,
                                                const float* __restrict__ scale,
                                                const float* __restrict__ Xin,
                                                float* __restrict__ Xout) {
    const int tid = blockIdx.x * 256 + threadIdx.x;
    const int r = tid >> 5;          // grid = kN*32/256 exactly
    const int lane = tid & 31;

    const int s = rs[r];
    const int e = re[r];

    const float4* Xin4 = (const float4*)Xin;
    float4 acc = make_float4(0.f, 0.f, 0.f, 0.f);

    for (int base = s; base < e; base += 32) {
        int cl = 0;
        float vl = 0.f;
        if (base + lane < e) {
            const unsigned long long p = rec[base + lane];
            cl = (int)((unsigned int)p & 0x1FFFF);
            vl = __uint_as_float((unsigned int)(p >> 32));
        }
        const int m4 = (min(32, e - base) + 3) & ~3;
        for (int j = 0; j < m4; j += 4) {
            const int c0 = __shfl(cl, j, 32);
            const int c1 = __shfl(cl, j + 1, 32);
            const int c2 = __shfl(cl, j + 2, 32);
            const int c3 = __shfl(cl, j + 3, 32);
            const float w0 = __shfl(vl, j, 32);
            const float w1 = __shfl(vl, j + 1, 32);
            const float w2 = __shfl(vl, j + 2, 32);
            const float w3 = __shfl(vl, j + 3, 32);
            const float4 x0 = Xin4[(size_t)c0 * 32 + lane];
            const float4 x1 = Xin4[(size_t)c1 * 32 + lane];
            const float4 x2 = Xin4[(size_t)c2 * 32 + lane];
            const float4 x3 = Xin4[(size_t)c3 * 32 + lane];
            acc.x = fmaf(w0, x0.x, acc.x); acc.y = fmaf(w0, x0.y, acc.y);
            acc.z = fmaf(w0, x0.z, acc.z); acc.w = fmaf(w0, x0.w, acc.w);
            acc.x = fmaf(w1, x1.x, acc.x); acc.y = fmaf(w1, x1.y, acc.y);
            acc.z = fmaf(w1, x1.z, acc.z); acc.w = fmaf(w1, x1.w, acc.w);
            acc.x = fmaf(w2, x2.x, acc.x); acc.y = fmaf(w2, x2.y, acc.y);
            acc.z = fmaf(w2, x2.z, acc.z); acc.w = fmaf(w2, x2.w, acc.w);
            acc.x = fmaf(w3, x3.x, acc.x); acc.y = fmaf(w3, x3.y, acc.y);
            acc.z = fmaf(w3, x3.z, acc.z); acc.w = fmaf(w3, x3.w, acc.w);
        }
    }
    if (ROW_SCALE) {
        const float k = scale[r];
        acc.x *= k; acc.y *= k; acc.z *= k; acc.w *= k;
    }
    if (RELU) {
        acc.x = fmaxf(acc.x, 0.f); acc.y = fmaxf(acc.y, 0.f);
        acc.z = fmaxf(acc.z, 0.f); acc.w = fmaxf(acc.w, 0.f);
    }
    ((float4*)Xout)[(size_t)r * 32 + lane] = acc;
}

extern "C" void kernel_launch(void* const* d_in, const int* in_sizes, int n_in,
                              void* d_out, int out_size, void* d_ws, size_t ws_size,
                              hipStream_t stream) {
    const float* x    = (const float*)d_in[0];
    const float* W    = (const float*)d_in[1];
    const float* kern = (const float*)d_in[2];
    const int*   p0r  = (const int*)d_in[3];
    const int*   p0c  = (const int*)d_in[4];
    const float* p0v  = (const float*)d_in[5];
    const int*   p1r  = (const int*)d_in[6];
    const int*   p1c  = (const int*)d_in[7];
    const float* p1v  = (const float*)d_in[8];
    float* out = (float*)d_out;                // doubles as X' before final write

    // ws layout (16B-aligned slabs), total ~83 MB
    char* w = (char*)d_ws;
    size_t off = 0;
    float* Xt = (float*)(w + off);                    off += (size_t)kN * kF * 4;  // 51.2 MB
    unsigned short* Wt = (unsigned short*)(w + off);  off += 128 * 128 * 2;        // 32 KB
    int* gcur0 = (int*)(w + off);                     off += 2048;
    int* gcur1 = (int*)(w + off);                     off += 2048;
    int* rs0 = (int*)(w + off);                       off += (size_t)kN * 4;
    int* re0 = (int*)(w + off);                       off += (size_t)kN * 4;
    int* rs1 = (int*)(w + off);                       off += (size_t)kN * 4;
    int* re1 = (int*)(w + off);                       off += (size_t)kN * 4;      // 1.6 MB
    unsigned long long* stg0 = (unsigned long long*)(w + off);
    off += (size_t)kBuckets * kBucketCap * 8;                                      // 14.4 MB
    unsigned long long* stg1 = (unsigned long long*)(w + off);
    off += (size_t)kBuckets * kBucketCap * 8;                                      // 14.4 MB

    const int rowBlocks = kN * 32 / 256;       // 12500

    // 1) Wt = bf16(W^T); cursors init
    transpose_w<<<64, 256, 0, stream>>>(W, Wt, gcur0, gcur1);

    // 2) fused: X' = x@W  ||  bucket both edge lists
    fused_gemm_scatter<<<kGemmBlocks + 2 * kChunkBlocks, 256, 0, stream>>>(
        x, Wt, out, p0r, p0c, p0v, p1r, p1c, p1v, gcur0, gcur1, stg0, stg1);

    // 3) per-bucket sort to exact row order (both matrices)
    bucket_sort<<<2 * kBuckets, 256, 0, stream>>>(gcur0, gcur1, stg0, stg1,
                                                  rs0, re0, rs1, re1);

    // 4) Xt = kernel * (phi0 @ X')
    spmm_csr<true, false><<<rowBlocks, 256, 0, stream>>>(rs0, re0, stg0, kern, out, Xt);

    // 5) out = relu(phi1 @ Xt)
    spmm_csr<false, true><<<rowBlocks, 256, 0, stream>>>(rs1, re1, stg1, nullptr, Xt, out);
}

// Round 7
// 228.805 us; speedup vs baseline: 11.9855x; 1.4237x over previous
//
#include <hip/hip_runtime.h>

// Wavelet_Convolution: out = relu(phi1 @ (kernel * (phi0 @ (x @ W))))
// N=100000, F=128, NNZ=1.6M per sparse matrix (COO, int32 idx, f32 vals).
//
// Pipeline (5 dispatches):
//   1) transpose_w (+cursor init): Wt = bf16(W^T)
//   2) fused_gemm_scatter: [blocks 0..1562] X' = x@W (bf16 MFMA, bf16 store)
//                          [blocks 1563..1758] edges -> 256-row buckets
//   3) bucket_sort: per-bucket LDS counting sort -> exact row order in place
//   4) spmm_csr: Xt(bf16) = kernel * (phi0 @ X')   (gather bf16, f32 acc)
//   5) spmm_csr: out(f32) = relu(phi1 @ Xt)        (gather bf16, f32 acc)
//
// bf16 storage of the gather operands halves the random-gather traffic
// (256 B/edge), which round-6 counters showed to be the dominant cost
// (FETCH 388 MB per spmm dispatch).

constexpr int kN = 100000;
constexpr int kF = 128;
constexpr int kNNZ = 1600000;

constexpr int kBuckets = (kN + 255) / 256;                  // 391 (256-row buckets)
constexpr int kBucketCap = 4608;                            // mean 4096 + 8 sigma
constexpr int kChunk = 16384;                               // edges per scatter block
constexpr int kChunkBlocks = (kNNZ + kChunk - 1) / kChunk;  // 98
constexpr int kGemmBlocks = (kN + 63) / 64;                 // 1563

typedef short bf16x8 __attribute__((ext_vector_type(8)));
typedef float f32x4 __attribute__((ext_vector_type(4)));
typedef unsigned short ushort4v __attribute__((ext_vector_type(4)));
typedef unsigned short ushort8v __attribute__((ext_vector_type(8)));

__device__ __forceinline__ unsigned short f32_to_bf16(float f) {
    unsigned int u = __float_as_uint(f);
    u += 0x7fffu + ((u >> 16) & 1u);   // round-to-nearest-even
    return (unsigned short)(u >> 16);
}
__device__ __forceinline__ float bf16_to_f32(unsigned short h) {
    return __uint_as_float((unsigned int)h << 16);
}

// ---------------------------------------------------------------------------
// Wt[n][k] = bf16(W[k][n]); block 0 also inits bucket cursors.
// ---------------------------------------------------------------------------
__global__ __launch_bounds__(256) void transpose_w(const float* __restrict__ W,
                                                   unsigned short* __restrict__ Wt,
                                                   int* __restrict__ g0,
                                                   int* __restrict__ g1) {
    const int t = threadIdx.x;
    const int e = blockIdx.x * 256 + t;   // grid 64
    const int n = e & 127, k = e >> 7;
    Wt[n * 128 + k] = f32_to_bf16(W[e]);
    if (blockIdx.x == 0) {
        for (int i = t; i < kBuckets; i += 256) {
            g0[i] = i * kBucketCap;
            g1[i] = i * kBucketCap;
        }
    }
}

// ---------------------------------------------------------------------------
// Fused: GEMM (blocks 0..kGemmBlocks-1) + bucket scatter (rest).
// GEMM: X' = x @ W via mfma_f32_16x16x32_bf16, stored as bf16.
// Scatter record: hi32 = f32 val, lo32 = (localrow&255)<<17 | col (col<2^17).
// ---------------------------------------------------------------------------
__global__ __launch_bounds__(256) void fused_gemm_scatter(
    const float* __restrict__ x, const unsigned short* __restrict__ Wt,
    unsigned short* __restrict__ Xpb,
    const int* __restrict__ r0, const int* __restrict__ c0, const float* __restrict__ v0,
    const int* __restrict__ r1, const int* __restrict__ c1, const float* __restrict__ v1,
    int* __restrict__ gc0, int* __restrict__ gc1,
    unsigned long long* __restrict__ s0, unsigned long long* __restrict__ s1) {
    __shared__ __align__(16) char smem[64 * 128 * 2 + 128 * 128 * 2];  // 48 KB
    const int t = threadIdx.x;

    if (blockIdx.x < kGemmBlocks) {
        // ================= GEMM branch =================
        unsigned short* xs = (unsigned short*)smem;            // 64x128
        unsigned short* wt = xs + 64 * 128;                    // 128x128
        const int rowBase = blockIdx.x * 64;

        {
            const int lrow = t >> 2;
            const int q = t & 3;
            int srow = rowBase + lrow;
            if (srow >= kN) srow = kN - 1;
            const float4* xr = (const float4*)(x + (size_t)srow * kF) + q * 8;
            #pragma unroll
            for (int i = 0; i < 8; ++i) {
                const float4 f = xr[i];
                ushort4v h;
                h.x = f32_to_bf16(f.x); h.y = f32_to_bf16(f.y);
                h.z = f32_to_bf16(f.z); h.w = f32_to_bf16(f.w);
                const int kidx = q * 32 + i * 4;
                *(ushort4v*)&xs[lrow * 128 + (kidx ^ ((lrow & 7) << 3))] = h;
            }
        }
        {
            const ushort8v* Wt8 = (const ushort8v*)Wt;
            #pragma unroll
            for (int i = 0; i < 8; ++i) {
                const int c = i * 256 + t;
                const int n = c >> 4;
                const int kb = (c & 15) * 8;
                *(ushort8v*)&wt[n * 128 + (kb ^ ((n & 7) << 3))] = Wt8[c];
            }
        }
        __syncthreads();

        const int w = t >> 6;
        const int l = t & 63;
        const int lr = l & 15;
        const int lq = l >> 4;

        f32x4 acc[8];
        #pragma unroll
        for (int n = 0; n < 8; ++n) acc[n] = (f32x4){0.f, 0.f, 0.f, 0.f};

        const int arow = w * 16 + lr;
        #pragma unroll
        for (int ks = 0; ks < 4; ++ks) {
            const int akidx = ks * 32 + lq * 8;
            const bf16x8 a = *(const bf16x8*)&xs[arow * 128 + (akidx ^ ((arow & 7) << 3))];
            #pragma unroll
            for (int n = 0; n < 8; ++n) {
                const int bn = n * 16 + lr;
                const bf16x8 b = *(const bf16x8*)&wt[bn * 128 + (akidx ^ ((bn & 7) << 3))];
                acc[n] = __builtin_amdgcn_mfma_f32_16x16x32_bf16(a, b, acc[n], 0, 0, 0);
            }
        }

        // C/D layout: col = lr, row = lq*4 + j; store bf16 (2B scalar stores,
        // 16 lanes cover 32B contiguous per 16-col group)
        #pragma unroll
        for (int j = 0; j < 4; ++j) {
            const int row = rowBase + w * 16 + lq * 4 + j;
            if (row < kN) {
                unsigned short* orow = Xpb + (size_t)row * kF + lr;
                #pragma unroll
                for (int n = 0; n < 8; ++n) orow[n * 16] = f32_to_bf16(acc[n][j]);
            }
        }
    } else {
        // ================= scatter branch =================
        int* hist = (int*)smem;                 // kBuckets
        int* hbase = hist + kBuckets;           // kBuckets
        const int b = blockIdx.x - kGemmBlocks;
        const bool m1 = b >= kChunkBlocks;
        const int cb = m1 ? b - kChunkBlocks : b;
        const int* rows = m1 ? r1 : r0;
        const int* cols = m1 ? c1 : c0;
        const float* vals = m1 ? v1 : v0;
        int* gcur = m1 ? gc1 : gc0;
        unsigned long long* stg = m1 ? s1 : s0;

        for (int i = t; i < kBuckets; i += 256) hist[i] = 0;
        __syncthreads();

        const int base0 = cb * kChunk;
        for (int j = 0; j < kChunk; j += 256) {
            const int idx = base0 + j + t;
            if (idx < kNNZ) atomicAdd(&hist[rows[idx] >> 8], 1);
        }
        __syncthreads();

        for (int i = t; i < kBuckets; i += 256) {
            const int c = hist[i];
            hbase[i] = c ? atomicAdd(&gcur[i], c) : 0;
            hist[i] = 0;
        }
        __syncthreads();

        for (int j = 0; j < kChunk; j += 256) {
            const int idx = base0 + j + t;
            if (idx < kNNZ) {
                const int r = rows[idx];
                const int bk = r >> 8;
                const int pos = hbase[bk] + atomicAdd(&hist[bk], 1);
                const unsigned int key =
                    ((unsigned int)(r & 255) << 17) | (unsigned int)cols[idx];
                stg[pos] = ((unsigned long long)__float_as_uint(vals[idx]) << 32) | key;
            }
        }
    }
}

// ---------------------------------------------------------------------------
// Per-bucket LDS counting sort (in place) + emit per-row [rs, re).
// Grid: 2*kBuckets blocks (both matrices). LDS: 36.9KB recs + 3KB tables.
// ---------------------------------------------------------------------------
__global__ __launch_bounds__(256) void bucket_sort(
    const int* __restrict__ gc0, const int* __restrict__ gc1,
    unsigned long long* __restrict__ s0, unsigned long long* __restrict__ s1,
    int* __restrict__ rs0, int* __restrict__ re0,
    int* __restrict__ rs1, int* __restrict__ re1) {
    __shared__ unsigned long long recs[kBucketCap];  // 36.9 KB
    __shared__ int hist[256];
    __shared__ int sc[256];
    __shared__ int cur[256];

    const int b = blockIdx.x;
    const bool m1 = b >= kBuckets;
    const int bk = m1 ? b - kBuckets : b;
    const int* gcur = m1 ? gc1 : gc0;
    unsigned long long* stg = m1 ? s1 : s0;
    int* rs = m1 ? rs1 : rs0;
    int* re = m1 ? re1 : re0;

    const int t = threadIdx.x;
    const int start = bk * kBucketCap;
    const int nrec = gcur[bk] - start;

    hist[t] = 0;
    __syncthreads();

    for (int i = t; i < nrec; i += 256) {
        const unsigned long long p = stg[start + i];
        recs[i] = p;
        atomicAdd(&hist[((unsigned int)p >> 17) & 255], 1);
    }
    __syncthreads();

    const int v = hist[t];
    sc[t] = v;
    __syncthreads();
    #pragma unroll
    for (int off = 1; off < 256; off <<= 1) {
        const int add = (t >= off) ? sc[t - off] : 0;
        __syncthreads();
        sc[t] += add;
        __syncthreads();
    }
    {
        const int ex = sc[t] - v;      // exclusive
        cur[t] = ex;
        const int row = bk * 256 + t;
        if (row < kN) {
            rs[row] = start + ex;
            re[row] = start + sc[t];
        }
    }
    __syncthreads();

    for (int i = t; i < nrec; i += 256) {
        const unsigned long long p = recs[i];
        const int lr = (int)(((unsigned int)p >> 17) & 255);
        const int pos = atomicAdd(&cur[lr], 1);
        stg[start + pos] = p;
    }
}

// ---------------------------------------------------------------------------
// Gather SpMM (bf16 input, f32 accumulate): 32 lanes per row.
// Coalesced rec load per 32-edge chunk, shuffle-broadcast, 4-wide unrolled
// 8B bf16x4 gathers. OUT_BF16 selects bf16 vs f32 output.
// ---------------------------------------------------------------------------
template <bool ROW_SCALE, bool RELU, bool OUT_BF16>
__global__ __launch_bounds__(256) void spmm_csr(const int* __restrict__ rs,
                                                const int* __restrict__ re,
                                                const unsigned long long* __restrict__ rec,
                                                const float* __restrict__ scale,
                                                const unsigned short* __restrict__ Xin,
                                                void* __restrict__ Xout) {
    const int tid = blockIdx.x * 256 + threadIdx.x;
    const int r = tid >> 5;          // grid = kN*32/256 exactly
    const int lane = tid & 31;

    const int s = rs[r];
    const int e = re[r];

    float4 acc = make_float4(0.f, 0.f, 0.f, 0.f);

    for (int base = s; base < e; base += 32) {
        int cl = 0;
        float vl = 0.f;
        if (base + lane < e) {
            const unsigned long long p = rec[base + lane];
            cl = (int)((unsigned int)p & 0x1FFFF);
            vl = __uint_as_float((unsigned int)(p >> 32));
        }
        const int m4 = (min(32, e - base) + 3) & ~3;
        for (int j = 0; j < m4; j += 4) {
            const int c0 = __shfl(cl, j, 32);
            const int c1 = __shfl(cl, j + 1, 32);
            const int c2 = __shfl(cl, j + 2, 32);
            const int c3 = __shfl(cl, j + 3, 32);
            const float w0 = __shfl(vl, j, 32);
            const float w1 = __shfl(vl, j + 1, 32);
            const float w2 = __shfl(vl, j + 2, 32);
            const float w3 = __shfl(vl, j + 3, 32);
            const ushort4v x0 = *(const ushort4v*)(Xin + (size_t)c0 * kF + lane * 4);
            const ushort4v x1 = *(const ushort4v*)(Xin + (size_t)c1 * kF + lane * 4);
            const ushort4v x2 = *(const ushort4v*)(Xin + (size_t)c2 * kF + lane * 4);
            const ushort4v x3 = *(const ushort4v*)(Xin + (size_t)c3 * kF + lane * 4);
            acc.x = fmaf(w0, bf16_to_f32(x0.x), acc.x);
            acc.y = fmaf(w0, bf16_to_f32(x0.y), acc.y);
            acc.z = fmaf(w0, bf16_to_f32(x0.z), acc.z);
            acc.w = fmaf(w0, bf16_to_f32(x0.w), acc.w);
            acc.x = fmaf(w1, bf16_to_f32(x1.x), acc.x);
            acc.y = fmaf(w1, bf16_to_f32(x1.y), acc.y);
            acc.z = fmaf(w1, bf16_to_f32(x1.z), acc.z);
            acc.w = fmaf(w1, bf16_to_f32(x1.w), acc.w);
            acc.x = fmaf(w2, bf16_to_f32(x2.x), acc.x);
            acc.y = fmaf(w2, bf16_to_f32(x2.y), acc.y);
            acc.z = fmaf(w2, bf16_to_f32(x2.z), acc.z);
            acc.w = fmaf(w2, bf16_to_f32(x2.w), acc.w);
            acc.x = fmaf(w3, bf16_to_f32(x3.x), acc.x);
            acc.y = fmaf(w3, bf16_to_f32(x3.y), acc.y);
            acc.z = fmaf(w3, bf16_to_f32(x3.z), acc.z);
            acc.w = fmaf(w3, bf16_to_f32(x3.w), acc.w);
        }
    }
    if (ROW_SCALE) {
        const float k = scale[r];
        acc.x *= k; acc.y *= k; acc.z *= k; acc.w *= k;
    }
    if (RELU) {
        acc.x = fmaxf(acc.x, 0.f); acc.y = fmaxf(acc.y, 0.f);
        acc.z = fmaxf(acc.z, 0.f); acc.w = fmaxf(acc.w, 0.f);
    }
    if (OUT_BF16) {
        ushort4v o;
        o.x = f32_to_bf16(acc.x); o.y = f32_to_bf16(acc.y);
        o.z = f32_to_bf16(acc.z); o.w = f32_to_bf16(acc.w);
        *(ushort4v*)((unsigned short*)Xout + (size_t)r * kF + lane * 4) = o;
    } else {
        ((float4*)Xout)[(size_t)r * 32 + lane] = acc;
    }
}

extern "C" void kernel_launch(void* const* d_in, const int* in_sizes, int n_in,
                              void* d_out, int out_size, void* d_ws, size_t ws_size,
                              hipStream_t stream) {
    const float* x    = (const float*)d_in[0];
    const float* W    = (const float*)d_in[1];
    const float* kern = (const float*)d_in[2];
    const int*   p0r  = (const int*)d_in[3];
    const int*   p0c  = (const int*)d_in[4];
    const float* p0v  = (const float*)d_in[5];
    const int*   p1r  = (const int*)d_in[6];
    const int*   p1c  = (const int*)d_in[7];
    const float* p1v  = (const float*)d_in[8];
    float* out = (float*)d_out;

    // ws layout (16B-aligned slabs), total ~60 MB
    char* w = (char*)d_ws;
    size_t off = 0;
    unsigned short* Xpb = (unsigned short*)(w + off); off += (size_t)kN * kF * 2; // 25.6 MB
    unsigned short* Xtb = (unsigned short*)(w + off); off += (size_t)kN * kF * 2; // 25.6 MB
    unsigned short* Wt = (unsigned short*)(w + off);  off += 128 * 128 * 2;       // 32 KB
    int* gcur0 = (int*)(w + off);                     off += 2048;
    int* gcur1 = (int*)(w + off);                     off += 2048;
    int* rs0 = (int*)(w + off);                       off += (size_t)kN * 4;
    int* re0 = (int*)(w + off);                       off += (size_t)kN * 4;
    int* rs1 = (int*)(w + off);                       off += (size_t)kN * 4;
    int* re1 = (int*)(w + off);                       off += (size_t)kN * 4;      // 1.6 MB
    unsigned long long* stg0 = (unsigned long long*)(w + off);
    off += (size_t)kBuckets * kBucketCap * 8;                                     // 14.4 MB
    unsigned long long* stg1 = (unsigned long long*)(w + off);
    off += (size_t)kBuckets * kBucketCap * 8;                                     // 14.4 MB

    const int rowBlocks = kN * 32 / 256;       // 12500

    // 1) Wt = bf16(W^T); cursors init
    transpose_w<<<64, 256, 0, stream>>>(W, Wt, gcur0, gcur1);

    // 2) fused: X'(bf16) = x@W  ||  bucket both edge lists
    fused_gemm_scatter<<<kGemmBlocks + 2 * kChunkBlocks, 256, 0, stream>>>(
        x, Wt, Xpb, p0r, p0c, p0v, p1r, p1c, p1v, gcur0, gcur1, stg0, stg1);

    // 3) per-bucket sort to exact row order (both matrices)
    bucket_sort<<<2 * kBuckets, 256, 0, stream>>>(gcur0, gcur1, stg0, stg1,
                                                  rs0, re0, rs1, re1);

    // 4) Xt(bf16) = kernel * (phi0 @ X')
    spmm_csr<true, false, true><<<rowBlocks, 256, 0, stream>>>(
        rs0, re0, stg0, kern, Xpb, Xtb);

    // 5) out(f32) = relu(phi1 @ Xt)
    spmm_csr<false, true, false><<<rowBlocks, 256, 0, stream>>>(
        rs1, re1, stg1, nullptr, Xtb, out);
}

// Round 8
// 206.871 us; speedup vs baseline: 13.2563x; 1.1060x over previous
//
#include <hip/hip_runtime.h>

// Wavelet_Convolution: out = relu(phi1 @ (kernel * (phi0 @ (x @ W))))
// N=100000, F=128, NNZ=1.6M per sparse matrix (COO, int32 idx, f32 vals).
//
// Pipeline (5 dispatches):
//   1) transpose_w (+cursor init): Wt = bf16(W^T)
//   2) fused_gemm_scatter: [blocks 0..391]    edges -> 256-row buckets
//                          [blocks 392..1954] X' = x@W (bf16 MFMA, bf16 store)
//      B-fragments read from global Wt (L1/L2-resident, shared by all blocks)
//      -> LDS = 16KB only -> high occupancy for both branches.
//   3) bucket_sort: per-bucket LDS counting sort -> exact row order in place
//   4) spmm_csr: Xt(bf16) = kernel * (phi0 @ X')   (gather bf16, f32 acc)
//   5) spmm_csr: out(f32) = relu(phi1 @ Xt)        (gather bf16, f32 acc)

constexpr int kN = 100000;
constexpr int kF = 128;
constexpr int kNNZ = 1600000;

constexpr int kBuckets = (kN + 255) / 256;                  // 391 (256-row buckets)
constexpr int kBucketCap = 4608;                            // mean 4096 + 8 sigma
constexpr int kChunk = 8192;                                // edges per scatter block
constexpr int kChunkBlocks = (kNNZ + kChunk - 1) / kChunk;  // 196 per matrix
constexpr int kScatBlocks = 2 * kChunkBlocks;               // 392
constexpr int kGemmBlocks = (kN + 63) / 64;                 // 1563

typedef short bf16x8 __attribute__((ext_vector_type(8)));
typedef float f32x4 __attribute__((ext_vector_type(4)));
typedef unsigned short ushort4v __attribute__((ext_vector_type(4)));

__device__ __forceinline__ unsigned short f32_to_bf16(float f) {
    unsigned int u = __float_as_uint(f);
    u += 0x7fffu + ((u >> 16) & 1u);   // round-to-nearest-even
    return (unsigned short)(u >> 16);
}
__device__ __forceinline__ float bf16_to_f32(unsigned short h) {
    return __uint_as_float((unsigned int)h << 16);
}

// ---------------------------------------------------------------------------
// Wt[n][k] = bf16(W[k][n]); block 0 also inits bucket cursors.
// ---------------------------------------------------------------------------
__global__ __launch_bounds__(256) void transpose_w(const float* __restrict__ W,
                                                   unsigned short* __restrict__ Wt,
                                                   int* __restrict__ g0,
                                                   int* __restrict__ g1) {
    const int t = threadIdx.x;
    const int e = blockIdx.x * 256 + t;   // grid 64
    const int n = e & 127, k = e >> 7;
    Wt[n * 128 + k] = f32_to_bf16(W[e]);
    if (blockIdx.x == 0) {
        for (int i = t; i < kBuckets; i += 256) {
            g0[i] = i * kBucketCap;
            g1[i] = i * kBucketCap;
        }
    }
}

// ---------------------------------------------------------------------------
// Fused: bucket scatter (blocks 0..kScatBlocks-1) + GEMM (rest).
// GEMM: X' = x @ W via mfma_f32_16x16x32_bf16; A-tile in LDS (swizzled),
// B-fragments straight from global Wt. Output stored bf16.
// Scatter record: hi32 = f32 val, lo32 = (localrow&255)<<17 | col (col<2^17).
// ---------------------------------------------------------------------------
__global__ __launch_bounds__(256) void fused_gemm_scatter(
    const float* __restrict__ x, const unsigned short* __restrict__ Wt,
    unsigned short* __restrict__ Xpb,
    const int* __restrict__ r0, const int* __restrict__ c0, const float* __restrict__ v0,
    const int* __restrict__ r1, const int* __restrict__ c1, const float* __restrict__ v1,
    int* __restrict__ gc0, int* __restrict__ gc1,
    unsigned long long* __restrict__ s0, unsigned long long* __restrict__ s1) {
    __shared__ __align__(16) char smem[64 * 128 * 2];   // 16 KB (union of branches)
    const int t = threadIdx.x;

    if (blockIdx.x >= kScatBlocks) {
        // ================= GEMM branch =================
        unsigned short* xs = (unsigned short*)smem;            // 64x128 bf16
        const int rowBase = (blockIdx.x - kScatBlocks) * 64;

        {
            const int lrow = t >> 2;
            const int q = t & 3;
            int srow = rowBase + lrow;
            if (srow >= kN) srow = kN - 1;
            const float4* xr = (const float4*)(x + (size_t)srow * kF) + q * 8;
            #pragma unroll
            for (int i = 0; i < 8; ++i) {
                const float4 f = xr[i];
                ushort4v h;
                h.x = f32_to_bf16(f.x); h.y = f32_to_bf16(f.y);
                h.z = f32_to_bf16(f.z); h.w = f32_to_bf16(f.w);
                const int kidx = q * 32 + i * 4;
                *(ushort4v*)&xs[lrow * 128 + (kidx ^ ((lrow & 7) << 3))] = h;
            }
        }
        __syncthreads();

        const int w = t >> 6;
        const int l = t & 63;
        const int lr = l & 15;
        const int lq = l >> 4;

        f32x4 acc[8];
        #pragma unroll
        for (int n = 0; n < 8; ++n) acc[n] = (f32x4){0.f, 0.f, 0.f, 0.f};

        const int arow = w * 16 + lr;
        #pragma unroll
        for (int ks = 0; ks < 4; ++ks) {
            const int akidx = ks * 32 + lq * 8;
            const bf16x8 a = *(const bf16x8*)&xs[arow * 128 + (akidx ^ ((arow & 7) << 3))];
            #pragma unroll
            for (int n = 0; n < 8; ++n) {
                const int bn = n * 16 + lr;
                const bf16x8 b = *(const bf16x8*)(Wt + bn * 128 + akidx);  // global, L1/L2
                acc[n] = __builtin_amdgcn_mfma_f32_16x16x32_bf16(a, b, acc[n], 0, 0, 0);
            }
        }

        // C/D layout: col = lr, row = lq*4 + j
        #pragma unroll
        for (int j = 0; j < 4; ++j) {
            const int row = rowBase + w * 16 + lq * 4 + j;
            if (row < kN) {
                unsigned short* orow = Xpb + (size_t)row * kF + lr;
                #pragma unroll
                for (int n = 0; n < 8; ++n) orow[n * 16] = f32_to_bf16(acc[n][j]);
            }
        }
    } else {
        // ================= scatter branch =================
        int* hist = (int*)smem;                 // kBuckets
        int* hbase = hist + kBuckets;           // kBuckets
        const int b = blockIdx.x;
        const bool m1 = b >= kChunkBlocks;
        const int cb = m1 ? b - kChunkBlocks : b;
        const int* rows = m1 ? r1 : r0;
        const int* cols = m1 ? c1 : c0;
        const float* vals = m1 ? v1 : v0;
        int* gcur = m1 ? gc1 : gc0;
        unsigned long long* stg = m1 ? s1 : s0;

        for (int i = t; i < kBuckets; i += 256) hist[i] = 0;
        __syncthreads();

        const int base0 = cb * kChunk;
        for (int j = 0; j < kChunk; j += 256) {
            const int idx = base0 + j + t;
            if (idx < kNNZ) atomicAdd(&hist[rows[idx] >> 8], 1);
        }
        __syncthreads();

        for (int i = t; i < kBuckets; i += 256) {
            const int c = hist[i];
            hbase[i] = c ? atomicAdd(&gcur[i], c) : 0;
            hist[i] = 0;
        }
        __syncthreads();

        for (int j = 0; j < kChunk; j += 256) {
            const int idx = base0 + j + t;
            if (idx < kNNZ) {
                const int r = rows[idx];
                const int bk = r >> 8;
                const int pos = hbase[bk] + atomicAdd(&hist[bk], 1);
                const unsigned int key =
                    ((unsigned int)(r & 255) << 17) | (unsigned int)cols[idx];
                stg[pos] = ((unsigned long long)__float_as_uint(vals[idx]) << 32) | key;
            }
        }
    }
}

// ---------------------------------------------------------------------------
// Per-bucket LDS counting sort (in place) + emit per-row [rs, re).
// Grid: 2*kBuckets blocks (both matrices). LDS: 36.9KB recs + 3KB tables.
// ---------------------------------------------------------------------------
__global__ __launch_bounds__(256) void bucket_sort(
    const int* __restrict__ gc0, const int* __restrict__ gc1,
    unsigned long long* __restrict__ s0, unsigned long long* __restrict__ s1,
    int* __restrict__ rs0, int* __restrict__ re0,
    int* __restrict__ rs1, int* __restrict__ re1) {
    __shared__ unsigned long long recs[kBucketCap];  // 36.9 KB
    __shared__ int hist[256];
    __shared__ int sc[256];
    __shared__ int cur[256];

    const int b = blockIdx.x;
    const bool m1 = b >= kBuckets;
    const int bk = m1 ? b - kBuckets : b;
    const int* gcur = m1 ? gc1 : gc0;
    unsigned long long* stg = m1 ? s1 : s0;
    int* rs = m1 ? rs1 : rs0;
    int* re = m1 ? re1 : re0;

    const int t = threadIdx.x;
    const int start = bk * kBucketCap;
    const int nrec = gcur[bk] - start;

    hist[t] = 0;
    __syncthreads();

    for (int i = t; i < nrec; i += 256) {
        const unsigned long long p = stg[start + i];
        recs[i] = p;
        atomicAdd(&hist[((unsigned int)p >> 17) & 255], 1);
    }
    __syncthreads();

    const int v = hist[t];
    sc[t] = v;
    __syncthreads();
    #pragma unroll
    for (int off = 1; off < 256; off <<= 1) {
        const int add = (t >= off) ? sc[t - off] : 0;
        __syncthreads();
        sc[t] += add;
        __syncthreads();
    }
    {
        const int ex = sc[t] - v;      // exclusive
        cur[t] = ex;
        const int row = bk * 256 + t;
        if (row < kN) {
            rs[row] = start + ex;
            re[row] = start + sc[t];
        }
    }
    __syncthreads();

    for (int i = t; i < nrec; i += 256) {
        const unsigned long long p = recs[i];
        const int lr = (int)(((unsigned int)p >> 17) & 255);
        const int pos = atomicAdd(&cur[lr], 1);
        stg[start + pos] = p;
    }
}

// ---------------------------------------------------------------------------
// Gather SpMM (bf16 input, f32 accumulate): 32 lanes per row.
// Coalesced rec load per 32-edge chunk, shuffle-broadcast, 4-wide unrolled
// 8B bf16x4 gathers. OUT_BF16 selects bf16 vs f32 output.
// ---------------------------------------------------------------------------
template <bool ROW_SCALE, bool RELU, bool OUT_BF16>
__global__ __launch_bounds__(256) void spmm_csr(const int* __restrict__ rs,
                                                const int* __restrict__ re,
                                                const unsigned long long* __restrict__ rec,
                                                const float* __restrict__ scale,
                                                const unsigned short* __restrict__ Xin,
                                                void* __restrict__ Xout) {
    const int tid = blockIdx.x * 256 + threadIdx.x;
    const int r = tid >> 5;          // grid = kN*32/256 exactly
    const int lane = tid & 31;

    const int s = rs[r];
    const int e = re[r];

    float4 acc = make_float4(0.f, 0.f, 0.f, 0.f);

    for (int base = s; base < e; base += 32) {
        int cl = 0;
        float vl = 0.f;
        if (base + lane < e) {
            const unsigned long long p = rec[base + lane];
            cl = (int)((unsigned int)p & 0x1FFFF);
            vl = __uint_as_float((unsigned int)(p >> 32));
        }
        const int m4 = (min(32, e - base) + 3) & ~3;
        for (int j = 0; j < m4; j += 4) {
            const int c0 = __shfl(cl, j, 32);
            const int c1 = __shfl(cl, j + 1, 32);
            const int c2 = __shfl(cl, j + 2, 32);
            const int c3 = __shfl(cl, j + 3, 32);
            const float w0 = __shfl(vl, j, 32);
            const float w1 = __shfl(vl, j + 1, 32);
            const float w2 = __shfl(vl, j + 2, 32);
            const float w3 = __shfl(vl, j + 3, 32);
            const ushort4v x0 = *(const ushort4v*)(Xin + (size_t)c0 * kF + lane * 4);
            const ushort4v x1 = *(const ushort4v*)(Xin + (size_t)c1 * kF + lane * 4);
            const ushort4v x2 = *(const ushort4v*)(Xin + (size_t)c2 * kF + lane * 4);
            const ushort4v x3 = *(const ushort4v*)(Xin + (size_t)c3 * kF + lane * 4);
            acc.x = fmaf(w0, bf16_to_f32(x0.x), acc.x);
            acc.y = fmaf(w0, bf16_to_f32(x0.y), acc.y);
            acc.z = fmaf(w0, bf16_to_f32(x0.z), acc.z);
            acc.w = fmaf(w0, bf16_to_f32(x0.w), acc.w);
            acc.x = fmaf(w1, bf16_to_f32(x1.x), acc.x);
            acc.y = fmaf(w1, bf16_to_f32(x1.y), acc.y);
            acc.z = fmaf(w1, bf16_to_f32(x1.z), acc.z);
            acc.w = fmaf(w1, bf16_to_f32(x1.w), acc.w);
            acc.x = fmaf(w2, bf16_to_f32(x2.x), acc.x);
            acc.y = fmaf(w2, bf16_to_f32(x2.y), acc.y);
            acc.z = fmaf(w2, bf16_to_f32(x2.z), acc.z);
            acc.w = fmaf(w2, bf16_to_f32(x2.w), acc.w);
            acc.x = fmaf(w3, bf16_to_f32(x3.x), acc.x);
            acc.y = fmaf(w3, bf16_to_f32(x3.y), acc.y);
            acc.z = fmaf(w3, bf16_to_f32(x3.z), acc.z);
            acc.w = fmaf(w3, bf16_to_f32(x3.w), acc.w);
        }
    }
    if (ROW_SCALE) {
        const float k = scale[r];
        acc.x *= k; acc.y *= k; acc.z *= k; acc.w *= k;
    }
    if (RELU) {
        acc.x = fmaxf(acc.x, 0.f); acc.y = fmaxf(acc.y, 0.f);
        acc.z = fmaxf(acc.z, 0.f); acc.w = fmaxf(acc.w, 0.f);
    }
    if (OUT_BF16) {
        ushort4v o;
        o.x = f32_to_bf16(acc.x); o.y = f32_to_bf16(acc.y);
        o.z = f32_to_bf16(acc.z); o.w = f32_to_bf16(acc.w);
        *(ushort4v*)((unsigned short*)Xout + (size_t)r * kF + lane * 4) = o;
    } else {
        ((float4*)Xout)[(size_t)r * 32 + lane] = acc;
    }
}

extern "C" void kernel_launch(void* const* d_in, const int* in_sizes, int n_in,
                              void* d_out, int out_size, void* d_ws, size_t ws_size,
                              hipStream_t stream) {
    const float* x    = (const float*)d_in[0];
    const float* W    = (const float*)d_in[1];
    const float* kern = (const float*)d_in[2];
    const int*   p0r  = (const int*)d_in[3];
    const int*   p0c  = (const int*)d_in[4];
    const float* p0v  = (const float*)d_in[5];
    const int*   p1r  = (const int*)d_in[6];
    const int*   p1c  = (const int*)d_in[7];
    const float* p1v  = (const float*)d_in[8];
    float* out = (float*)d_out;

    // ws layout (16B-aligned slabs), total ~60 MB
    char* w = (char*)d_ws;
    size_t off = 0;
    unsigned short* Xpb = (unsigned short*)(w + off); off += (size_t)kN * kF * 2; // 25.6 MB
    unsigned short* Xtb = (unsigned short*)(w + off); off += (size_t)kN * kF * 2; // 25.6 MB
    unsigned short* Wt = (unsigned short*)(w + off);  off += 128 * 128 * 2;       // 32 KB
    int* gcur0 = (int*)(w + off);                     off += 2048;
    int* gcur1 = (int*)(w + off);                     off += 2048;
    int* rs0 = (int*)(w + off);                       off += (size_t)kN * 4;
    int* re0 = (int*)(w + off);                       off += (size_t)kN * 4;
    int* rs1 = (int*)(w + off);                       off += (size_t)kN * 4;
    int* re1 = (int*)(w + off);                       off += (size_t)kN * 4;      // 1.6 MB
    unsigned long long* stg0 = (unsigned long long*)(w + off);
    off += (size_t)kBuckets * kBucketCap * 8;                                     // 14.4 MB
    unsigned long long* stg1 = (unsigned long long*)(w + off);
    off += (size_t)kBuckets * kBucketCap * 8;                                     // 14.4 MB

    const int rowBlocks = kN * 32 / 256;       // 12500

    // 1) Wt = bf16(W^T); cursors init
    transpose_w<<<64, 256, 0, stream>>>(W, Wt, gcur0, gcur1);

    // 2) fused: bucket both edge lists (first 392 blocks) || X'(bf16) = x@W
    fused_gemm_scatter<<<kScatBlocks + kGemmBlocks, 256, 0, stream>>>(
        x, Wt, Xpb, p0r, p0c, p0v, p1r, p1c, p1v, gcur0, gcur1, stg0, stg1);

    // 3) per-bucket sort to exact row order (both matrices)
    bucket_sort<<<2 * kBuckets, 256, 0, stream>>>(gcur0, gcur1, stg0, stg1,
                                                  rs0, re0, rs1, re1);

    // 4) Xt(bf16) = kernel * (phi0 @ X')
    spmm_csr<true, false, true><<<rowBlocks, 256, 0, stream>>>(
        rs0, re0, stg0, kern, Xpb, Xtb);

    // 5) out(f32) = relu(phi1 @ Xt)
    spmm_csr<false, true, false><<<rowBlocks, 256, 0, stream>>>(
        rs1, re1, stg1, nullptr, Xtb, out);
}